// Round 5
// baseline (114.059 us; speedup 1.0000x reference)
//
#include <hip/hip_runtime.h>
#include <hip/hip_fp16.h>

// HartleyConv2d: out[b,o,u,v] = (0.5/132^2) * sum_c [ X*(W+Wf) + Xf*(W-Wf) ]
// X = DHT2(pad1(x) zero-padded to 132); DHT table T[r][k] = cas(2pi r (k+1)/132).
// ALL I/O fp32: x [8,64,128,128], w [64,64,3,3], out [8,64,128,128].
// R12: dht2 grid exactly 512 (hgT prep folded in as per-block prologue units,
//      cfT in block 16 -> no 67-block second round); Tfl fill via incremental
//      add-fold mod (ci fixed per thread); combine split into sequential u1/u2
//      nt-loops + __launch_bounds__(256,4) to cap VGPR<=128 -> 4 blocks/CU ->
//      528 blocks co-resident in ONE round (kills potential 16-block tail).

#define SCALE (0.5f / 17424.0f)
#define MFMA  __builtin_amdgcn_mfma_f32_16x16x32_f16

typedef __attribute__((ext_vector_type(8))) _Float16 f16x8;
typedef __attribute__((ext_vector_type(4))) _Float16 f16x4;
typedef __attribute__((ext_vector_type(4))) float    f32x4;

// --------------------------------------------------------------- prep bits --
// one hgT unit = (u, it): 512 threads each handle oc = it*512+tid.
static __device__ __forceinline__ void prep_hg_unit(
    int unit, int tid, const float* __restrict__ w, _Float16* __restrict__ hgT)
{
    const int u = unit >> 3, it = unit & 7;
    const float step = 6.28318530717958647692f / 132.0f;
    float a[3], ap[3];
    a[0] = 1.f; ap[0] = 1.f;
    #pragma unroll
    for (int i = 1; i < 3; ++i) {
        float s, c;
        sincosf((float)((u * i) % 132) * step, &s, &c);
        a[i] = c + s;                                   // cas(2pi*u*i/132)
        sincosf((float)(((u + 1) * i) % 132) * step, &s, &c);
        ap[i] = c - s;                                  // cas(-2pi*(u+1)*i/132)
    }
    const int oc = it * 512 + tid;                      // o*64+c, 0..4095
    const float* wp = w + (size_t)oc * 9;
    float w9[9];
    #pragma unroll
    for (int q = 0; q < 9; ++q) w9[q] = wp[q];
    #pragma unroll
    for (int j = 0; j < 3; ++j) {
        const float h = a[0]*w9[j] + a[1]*w9[3+j] + a[2]*w9[6+j];
        const float g = ap[0]*w9[j] + ap[1]*w9[3+j] + ap[2]*w9[6+j];
        hgT[((size_t)u * 6 + j)     * 4096 + oc] = (_Float16)h;
        hgT[((size_t)u * 6 + 3 + j) * 4096 + oc] = (_Float16)g;
    }
}

// ------------------------------------------------------------ dht2_all ------
// grid(512) x 512 thr (8 waves), 2 blocks/CU -> one full round, no tail.
// prologue: block bc runs hgT unit bc (bc<16 also unit 512+bc); block 16: cfT.
// pass A: wave wv owns i-tile wv: Y1l[v][i] = sum_j Tfl[v][j] * x[i][j]
// pass B: wave wv owns v-tile wv (0..127); tile 8 (v 128..131) waves 0-3.
// epilogue: acc -> Tfl (reuse) -> linear b128 copy-out. X rows padded to 136.
__global__ __launch_bounds__(512, 4) void dht2_all(
    const float* __restrict__ x, const float* __restrict__ w,
    _Float16* __restrict__ X, _Float16* __restrict__ cfT,
    _Float16* __restrict__ hgT)
{
    const int bc = blockIdx.x;
    const int tid = threadIdx.x, wv = tid >> 6, lane = tid & 63;
    const int col = lane & 15, quad = lane >> 4;
    const float step = 6.28318530717958647692f / 132.0f;
    __shared__ _Float16 Tfl[144][136];   // stride 136 (272 B): conflict-minimal
    __shared__ _Float16 Y1l[144][136];
    __shared__ float castab[132];        // cas(2pi*m/132)

    const float* xp = x + (size_t)bc * 16384;
    const int ic = wv * 16 + col;        // this wave's i-column (0..127)

    // ---- hoist x loads for this wave's i-tile (issued first, in flight)
    float4 xv[4][2];
    #pragma unroll
    for (int kc = 0; kc < 4; ++kc) {
        const int k0 = kc * 32 + quad * 8;
        xv[kc][0] = *(const float4*)(xp + ic * 128 + k0);
        xv[kc][1] = *(const float4*)(xp + ic * 128 + k0 + 4);
    }

    // ---- folded prep (fills x-load latency window; no extra blocks)
    prep_hg_unit(bc, tid, w, hgT);
    if (bc < 16) prep_hg_unit(512 + bc, tid, w, hgT);
    if (bc == 16 && tid < 128) {
        const int v = tid;
        float s, c;
        _Float16 o[8];
        o[0] = (_Float16)1.0f; o[3] = (_Float16)1.0f;
        o[6] = (_Float16)0.0f; o[7] = (_Float16)0.0f;
        sincosf((float)((v * 1) % 132) * step, &s, &c);       o[1] = (_Float16)(c + s);
        sincosf((float)((v * 2) % 132) * step, &s, &c);       o[2] = (_Float16)(c + s);
        sincosf((float)(((v + 1) * 1) % 132) * step, &s, &c); o[4] = (_Float16)(c - s);
        sincosf((float)(((v + 1) * 2) % 132) * step, &s, &c); o[5] = (_Float16)(c - s);
        *(f16x8*)(cfT + v * 8) = *(f16x8*)o;
    }

    // ---- cas table (132 sincosf across 512 threads)
    if (tid < 132) {
        float s, c;
        sincosf((float)tid * step, &s, &c);
        castab[tid] = c + s;
    }
    __syncthreads();

    // ---- fill Tfl[row][ci] = cas((row*(ci+1)) mod 132), rows >=132 zero.
    // ci fixed per thread, rows advance by 4 -> incremental add-fold mod.
    {
        const int ci = tid & 127;
        const int row0 = tid >> 7;           // 0..3
        int m  = (row0 * (ci + 1)) % 132;
        int dm = (4 * (ci + 1)) % 132;
        int row = row0;
        #pragma unroll
        for (int s = 0; s < 36; ++s) {
            const float v = (row < 132) ? castab[m] : 0.f;
            Tfl[row][ci] = (_Float16)v;
            row += 4;
            m += dm; if (m >= 132) m -= 132;
        }
    }
    // ---- convert x to f16 B-fragments
    f16x8 bfA[4];
    #pragma unroll
    for (int kc = 0; kc < 4; ++kc) {
        f16x8 t;
        t[0] = (_Float16)xv[kc][0].x; t[1] = (_Float16)xv[kc][0].y;
        t[2] = (_Float16)xv[kc][0].z; t[3] = (_Float16)xv[kc][0].w;
        t[4] = (_Float16)xv[kc][1].x; t[5] = (_Float16)xv[kc][1].y;
        t[6] = (_Float16)xv[kc][1].z; t[7] = (_Float16)xv[kc][1].w;
        bfA[kc] = t;
    }
    __syncthreads();

    // ---- pass A: 9 mt-tiles x 4 kc, all operands LDS/regs
    f32x4 accA[9];
    #pragma unroll
    for (int mt = 0; mt < 9; ++mt) accA[mt] = (f32x4)0.f;
    #pragma unroll
    for (int kc = 0; kc < 4; ++kc) {
        const int k0 = kc * 32 + quad * 8;
        #pragma unroll
        for (int mt = 0; mt < 9; ++mt) {
            const f16x8 af = *(const f16x8*)&Tfl[mt * 16 + col][k0];
            accA[mt] = MFMA(af, bfA[kc], accA[mt], 0, 0, 0);
        }
    }
    #pragma unroll
    for (int mt = 0; mt < 9; ++mt)
        #pragma unroll
        for (int r = 0; r < 4; ++r)
            Y1l[mt * 16 + quad * 4 + r][ic] = (_Float16)accA[mt][r];
    __syncthreads();

    // ---- pass B main: wave wv -> v-tile wv (v = wv*16+col, 0..127)
    f32x4 accB[9];
    #pragma unroll
    for (int mt = 0; mt < 9; ++mt) accB[mt] = (f32x4)0.f;
    #pragma unroll
    for (int kc = 0; kc < 4; ++kc) {
        const int k0 = kc * 32 + quad * 8;
        const f16x8 bf = *(const f16x8*)&Y1l[wv * 16 + col][k0];
        #pragma unroll
        for (int mt = 0; mt < 9; ++mt) {
            const f16x8 af = *(const f16x8*)&Tfl[mt * 16 + col][k0];
            accB[mt] = MFMA(af, bf, accB[mt], 0, 0, 0);
        }
    }
    // ---- tile 8 (v = 128..143, valid 128..131): waves 0..3
    // wave 0: mt {0,1,8}; wave 1: {2,3}; wave 2: {4,5}; wave 3: {6,7}
    f32x4 accT[3];
    #pragma unroll
    for (int j = 0; j < 3; ++j) accT[j] = (f32x4)0.f;
    if (wv < 4) {
        #pragma unroll
        for (int kc = 0; kc < 4; ++kc) {
            const int k0 = kc * 32 + quad * 8;
            const f16x8 bf = *(const f16x8*)&Y1l[128 + col][k0];
            #pragma unroll
            for (int j = 0; j < 3; ++j) {
                if (j < 2 || wv == 0) {
                    const int mt = (j == 2) ? 8 : (wv * 2 + j);
                    const f16x8 af = *(const f16x8*)&Tfl[mt * 16 + col][k0];
                    accT[j] = MFMA(af, bf, accT[j], 0, 0, 0);
                }
            }
        }
    }
    __syncthreads();                     // all Tfl/Y1l reads done

    // ---- restage X into Tfl (now dead): main tiles (v 0..127)
    #pragma unroll
    for (int mt = 0; mt < 9; ++mt)
        #pragma unroll
        for (int r = 0; r < 4; ++r)
            Tfl[mt * 16 + quad * 4 + r][wv * 16 + col] = (_Float16)accB[mt][r];
    // tile 8 (v 128..131)
    if (wv < 4 && col < 4) {
        #pragma unroll
        for (int j = 0; j < 3; ++j) {
            if (j < 2 || wv == 0) {
                const int mt = (j == 2) ? 8 : (wv * 2 + j);
                #pragma unroll
                for (int r = 0; r < 4; ++r)
                    Tfl[mt * 16 + quad * 4 + r][128 + col] = (_Float16)accT[j][r];
            }
        }
    }
    __syncthreads();
    // linear copy-out: 132 rows x 17 f16x8 chunks (cols 132..135 junk, unread)
    _Float16* Xp = X + (size_t)bc * 17952;
    #pragma unroll
    for (int s = 0; s < 5; ++s) {
        const int ch = tid + 512 * s;      // valid < 2244
        if (ch < 2244) {
            const int u = ch / 17, kk = ch - u * 17;
            *(f16x8*)(Xp + u * 136 + kk * 8) = *(const f16x8*)&Tfl[u][kk * 8];
        }
    }
}

// ---------------------------------------------------------- combine MFMA ----
// grid (66 uidx, 8 b), 256 thr (4 waves), 38KB LDS, VGPR capped at 128 via
// __launch_bounds__(256,4) -> 4 blocks/CU -> all 528 blocks in ONE round.
// Block stages P/M for u1=uidx ONCE and emits rows u1 AND u2=131-uidx
// (h(u2)=g(u1), g(u2)=h(u1), P(u2,v)=P(u1,131-v), M(u2,v)=-M(u1,131-v)).
// u1 and u2 emitted in SEQUENTIAL nt-loops (halves live accumulators; the
// Ps/Ms reads were already distinct addresses, so no extra LDS traffic).
__global__ __launch_bounds__(256, 4) void combine_mfma(
    const _Float16* __restrict__ X, const _Float16* __restrict__ hgT,
    const _Float16* __restrict__ cfT, float* __restrict__ out)
{
    const int uidx = blockIdx.x;    // 0..65
    const int b = blockIdx.y;       // 0..7
    const int tid = threadIdx.x;
    const int wv = tid >> 6, lane = tid & 63;
    const int col = lane & 15, quad = lane >> 4;
    const int u2 = 131 - uidx;
    const bool doB = (uidx >= 4);   // u2 <= 127

    __shared__ _Float16 Ps[132][72];   // [v][c], stride 72 (bank-safe)
    __shared__ _Float16 Ms[132][72];

    // ---- stage P/M for all v in 0..131
    {
        const int c = tid >> 2, sub = tid & 3;
        const _Float16* rowd = X + (size_t)(b * 64 + c) * 17952 + (size_t)uidx * 136;
        const _Float16* rowm = X + (size_t)(b * 64 + c) * 17952 + (size_t)u2 * 136;
        #pragma unroll
        for (int k = 0; k < 8; ++k) {
            const int v0 = sub * 32 + 4 * k;
            const f16x4 d = *(const f16x4*)(rowd + v0);
            const f16x4 m = *(const f16x4*)(rowm + (128 - v0));
            #pragma unroll
            for (int i = 0; i < 4; ++i) {
                Ps[v0 + i][c] = d[i] + m[3 - i];   // P(u,v)=X(u,v)+X(131-u,131-v)
                Ms[v0 + i][c] = d[i] - m[3 - i];
            }
        }
        if (sub == 0) {                            // tail v = 128..131
            const f16x4 d = *(const f16x4*)(rowd + 128);
            const f16x4 m = *(const f16x4*)(rowm);
            #pragma unroll
            for (int i = 0; i < 4; ++i) {
                Ps[128 + i][c] = d[i] + m[3 - i];
                Ms[128 + i][c] = d[i] - m[3 - i];
            }
        }
    }

    // ---- hoist h/g fragments for u1 (both output rows use them, swapped)
    const _Float16* hgu = hgT + (size_t)uidx * 6 * 4096;
    const int orow = wv * 16 + col;
    f16x8 hA[3][2], gA[3][2];
    #pragma unroll
    for (int kt = 0; kt < 3; ++kt)
        #pragma unroll
        for (int hf = 0; hf < 2; ++hf) {
            hA[kt][hf] = *(const f16x8*)(hgu + ((size_t)kt * 64 + orow) * 64 + hf * 32 + quad * 8);
            gA[kt][hf] = *(const f16x8*)(hgu + ((size_t)(3 + kt) * 64 + orow) * 64 + hf * 32 + quad * 8);
        }
    __syncthreads();

    float* outA = out + (((size_t)(b * 64 + wv * 16 + quad * 4)) * 128 + uidx) * 128 + col;
    float* outB = out + (((size_t)(b * 64 + wv * 16 + quad * 4)) * 128 + u2) * 128 + col;

    // ---- u1 rows: sum_kt bv_kt*(h_kt (x) P) + bp_kt*(g_kt (x) M)
    #pragma unroll
    for (int nt = 0; nt < 8; ++nt) {
        const int vA = nt * 16 + col;
        const f16x8 cf8 = *(const f16x8*)(cfT + (size_t)(nt * 16 + col) * 8);
        const float c1 = (float)cf8[1], c2 = (float)cf8[2];
        const float d1 = (float)cf8[4], d2 = (float)cf8[5];
        const f16x8 p0 = *(const f16x8*)&Ps[vA][quad * 8];
        const f16x8 p1 = *(const f16x8*)&Ps[vA][32 + quad * 8];
        const f16x8 m0 = *(const f16x8*)&Ms[vA][quad * 8];
        const f16x8 m1 = *(const f16x8*)&Ms[vA][32 + quad * 8];
        f32x4 aP0 = (f32x4)0.f, aP1 = (f32x4)0.f, aP2 = (f32x4)0.f;
        f32x4 aM0 = (f32x4)0.f, aM1 = (f32x4)0.f, aM2 = (f32x4)0.f;
        aP0 = MFMA(hA[0][0], p0, aP0, 0, 0, 0); aP0 = MFMA(hA[0][1], p1, aP0, 0, 0, 0);
        aP1 = MFMA(hA[1][0], p0, aP1, 0, 0, 0); aP1 = MFMA(hA[1][1], p1, aP1, 0, 0, 0);
        aP2 = MFMA(hA[2][0], p0, aP2, 0, 0, 0); aP2 = MFMA(hA[2][1], p1, aP2, 0, 0, 0);
        aM0 = MFMA(gA[0][0], m0, aM0, 0, 0, 0); aM0 = MFMA(gA[0][1], m1, aM0, 0, 0, 0);
        aM1 = MFMA(gA[1][0], m0, aM1, 0, 0, 0); aM1 = MFMA(gA[1][1], m1, aM1, 0, 0, 0);
        aM2 = MFMA(gA[2][0], m0, aM2, 0, 0, 0); aM2 = MFMA(gA[2][1], m1, aM2, 0, 0, 0);
        #pragma unroll
        for (int r = 0; r < 4; ++r)
            outA[(size_t)r * 16384 + nt * 16] =
                ((aP0[r] + c1 * aP1[r] + c2 * aP2[r]) +
                 (aM0[r] + d1 * aM1[r] + d2 * aM2[r])) * SCALE;
    }
    // ---- u2 rows: g on P(rev), h on M(rev), minus M-part
    if (doB) {
        #pragma unroll
        for (int nt = 0; nt < 8; ++nt) {
            const int vA = nt * 16 + col;
            const int vB = 131 - vA;
            const f16x8 cf8 = *(const f16x8*)(cfT + (size_t)(nt * 16 + col) * 8);
            const float c1 = (float)cf8[1], c2 = (float)cf8[2];
            const float d1 = (float)cf8[4], d2 = (float)cf8[5];
            const f16x8 p0 = *(const f16x8*)&Ps[vB][quad * 8];
            const f16x8 p1 = *(const f16x8*)&Ps[vB][32 + quad * 8];
            const f16x8 m0 = *(const f16x8*)&Ms[vB][quad * 8];
            const f16x8 m1 = *(const f16x8*)&Ms[vB][32 + quad * 8];
            f32x4 bP0 = (f32x4)0.f, bP1 = (f32x4)0.f, bP2 = (f32x4)0.f;
            f32x4 bM0 = (f32x4)0.f, bM1 = (f32x4)0.f, bM2 = (f32x4)0.f;
            bP0 = MFMA(gA[0][0], p0, bP0, 0, 0, 0); bP0 = MFMA(gA[0][1], p1, bP0, 0, 0, 0);
            bP1 = MFMA(gA[1][0], p0, bP1, 0, 0, 0); bP1 = MFMA(gA[1][1], p1, bP1, 0, 0, 0);
            bP2 = MFMA(gA[2][0], p0, bP2, 0, 0, 0); bP2 = MFMA(gA[2][1], p1, bP2, 0, 0, 0);
            bM0 = MFMA(hA[0][0], m0, bM0, 0, 0, 0); bM0 = MFMA(hA[0][1], m1, bM0, 0, 0, 0);
            bM1 = MFMA(hA[1][0], m0, bM1, 0, 0, 0); bM1 = MFMA(hA[1][1], m1, bM1, 0, 0, 0);
            bM2 = MFMA(hA[2][0], m0, bM2, 0, 0, 0); bM2 = MFMA(hA[2][1], m1, bM2, 0, 0, 0);
            #pragma unroll
            for (int r = 0; r < 4; ++r)
                outB[(size_t)r * 16384 + nt * 16] =
                    ((bP0[r] + c1 * bP1[r] + c2 * bP2[r]) -
                     (bM0[r] + d1 * bM1[r] + d2 * bM2[r])) * SCALE;
        }
    }
}

// ----------------------------------------------------------------- launch ----
extern "C" void kernel_launch(void* const* d_in, const int* in_sizes, int n_in,
                              void* d_out, int out_size, void* d_ws, size_t ws_size,
                              hipStream_t stream)
{
    const float* x = (const float*)d_in[0];   // fp32 [8,64,128,128]
    const float* w = (const float*)d_in[1];   // fp32 [64,64,3,3]
    char* ws = (char*)d_ws;
    // byte layout:
    //   cfT f16 @ 36,864     (2,048 B)       [128][8]
    //   X   f16 @ 65,536     (18,382,848 B)  [512][132][136] (cols 132..135 junk)
    //   hgT f16 @ 18,448,384 (3,244,032 B)   [66][6][64][64]
    // total ~21.7 MB
    _Float16* cfT = (_Float16*)(ws + 36864);
    _Float16* X   = (_Float16*)(ws + 65536);
    _Float16* hgT = (_Float16*)(ws + 18448384);

    // launch 1: dht2 (512 blocks, prep folded in -> exactly one block-round)
    dht2_all<<<dim3(512), dim3(512), 0, stream>>>(x, w, X, cfT, hgT);

    // launch 2: combine, u-paired, 4 blocks/CU -> 528 blocks in one round
    combine_mfma<<<dim3(66, 8), dim3(256), 0, stream>>>(
        X, hgT, cfT, (float*)d_out);
}

// Round 6
// 110.543 us; speedup vs baseline: 1.0318x; 1.0318x over previous
//
#include <hip/hip_runtime.h>
#include <hip/hip_fp16.h>

// HartleyConv2d: out[b,o,u,v] = (0.5/132^2) * sum_c [ X*(W+Wf) + Xf*(W-Wf) ]
// X = DHT2(pad1(x) zero-padded to 132); DHT table T[r][k] = cas(2pi r (k+1)/132).
// ALL I/O fp32: x [8,64,128,128], w [64,64,3,3], out [8,64,128,128].
// R13: revert to R11 (best measured 110.7us) -- R12's folded prep + seq u1/u2
//      split regressed +3.4us. Only delta vs R11: combine staging forward-row
//      loads widened to f16x8 (16 -> 12 load insts/thread, same math).

#define SCALE (0.5f / 17424.0f)
#define MFMA  __builtin_amdgcn_mfma_f32_16x16x32_f16

typedef __attribute__((ext_vector_type(8))) _Float16 f16x8;
typedef __attribute__((ext_vector_type(4))) _Float16 f16x4;
typedef __attribute__((ext_vector_type(4))) float    f32x4;

// ------------------------------------------------------- dht2_prep ----------
// bid 0..511   : dht2 for plane bc=bid (512 thr, 8 waves)
// bid 512..577 : hgT[u][kt][o][c] for u=bid-512 (all 4096 oc, 8 its of 512)
// bid 578      : cfT [128][8] f16 {1,bv1,bv2,1,bp1,bp2,0,0}
__global__ __launch_bounds__(512, 4) void dht2_prep(
    const float* __restrict__ x, const float* __restrict__ w,
    _Float16* __restrict__ X, _Float16* __restrict__ cfT,
    _Float16* __restrict__ hgT)
{
    const int tid = threadIdx.x;
    const float step = 6.28318530717958647692f / 132.0f;

    if (blockIdx.x >= 512) {
        const int bid2 = blockIdx.x - 512;     // 0..66
        if (bid2 == 66) {                      // ---- cfT
            if (tid < 128) {
                const int v = tid;
                float s, c;
                _Float16 o[8];
                o[0] = (_Float16)1.0f; o[3] = (_Float16)1.0f;
                o[6] = (_Float16)0.0f; o[7] = (_Float16)0.0f;
                sincosf((float)((v * 1) % 132) * step, &s, &c);       o[1] = (_Float16)(c + s);
                sincosf((float)((v * 2) % 132) * step, &s, &c);       o[2] = (_Float16)(c + s);
                sincosf((float)(((v + 1) * 1) % 132) * step, &s, &c); o[4] = (_Float16)(c - s);
                sincosf((float)(((v + 1) * 2) % 132) * step, &s, &c); o[5] = (_Float16)(c - s);
                *(f16x8*)(cfT + v * 8) = *(f16x8*)o;
            }
            return;
        }
        // ---- hgT for u = bid2 (0..65)
        const int u = bid2;
        float a[3], ap[3];
        a[0] = 1.f; ap[0] = 1.f;
        #pragma unroll
        for (int i = 1; i < 3; ++i) {
            float s, c;
            sincosf((float)((u * i) % 132) * step, &s, &c);
            a[i] = c + s;                                   // cas(2pi*u*i/132)
            sincosf((float)(((u + 1) * i) % 132) * step, &s, &c);
            ap[i] = c - s;                                  // cas(-2pi*(u+1)*i/132)
        }
        for (int it = 0; it < 8; ++it) {
            const int oc = it * 512 + tid;                  // o*64+c, 0..4095
            const float* wp = w + (size_t)oc * 9;
            float w9[9];
            #pragma unroll
            for (int q = 0; q < 9; ++q) w9[q] = wp[q];
            #pragma unroll
            for (int j = 0; j < 3; ++j) {
                const float h = a[0]*w9[j] + a[1]*w9[3+j] + a[2]*w9[6+j];
                const float g = ap[0]*w9[j] + ap[1]*w9[3+j] + ap[2]*w9[6+j];
                hgT[((size_t)u * 6 + j)     * 4096 + oc] = (_Float16)h;
                hgT[((size_t)u * 6 + 3 + j) * 4096 + oc] = (_Float16)g;
            }
        }
        return;
    }

    // ------------------------------------------------------ dht2 path ----
    // pass A: wave wv owns i-tile wv: Y1l[v][i] = sum_j Tfl[v][j] * x[i][j]
    // pass B: wave wv owns v-tile wv (0..127); tile 8 (v 128..131) waves 0-3.
    const int bc = blockIdx.x;
    const int wv = tid >> 6, lane = tid & 63;
    const int col = lane & 15, quad = lane >> 4;
    __shared__ _Float16 Tfl[144][136];   // stride 136 (272 B): conflict-minimal
    __shared__ _Float16 Y1l[144][136];
    __shared__ float castab[132];        // cas(2pi*m/132)

    const float* xp = x + (size_t)bc * 16384;
    const int ic = wv * 16 + col;        // this wave's i-column (0..127)

    // ---- hoist x loads for this wave's i-tile (in flight across barriers)
    float4 xv[4][2];
    #pragma unroll
    for (int kc = 0; kc < 4; ++kc) {
        const int k0 = kc * 32 + quad * 8;
        xv[kc][0] = *(const float4*)(xp + ic * 128 + k0);
        xv[kc][1] = *(const float4*)(xp + ic * 128 + k0 + 4);
    }
    // ---- cas table (one sincos per entry, 132 entries over 512 threads)
    if (tid < 132) {
        float s, c;
        sincosf((float)tid * step, &s, &c);
        castab[tid] = c + s;
    }
    __syncthreads();
    // ---- fill Tfl[row][ci] = cas((row*(ci+1)) mod 132), rows >=132 zero
    #pragma unroll
    for (int s = 0; s < 36; ++s) {
        const int idx = s * 512 + tid;       // 0..18431
        const int row = idx >> 7;            // 0..143
        const int ci  = idx & 127;
        float v = 0.f;
        if (row < 132) v = castab[(row * (ci + 1)) % 132];
        Tfl[row][ci] = (_Float16)v;
    }
    // ---- convert x to f16 B-fragments
    f16x8 bfA[4];
    #pragma unroll
    for (int kc = 0; kc < 4; ++kc) {
        f16x8 t;
        t[0] = (_Float16)xv[kc][0].x; t[1] = (_Float16)xv[kc][0].y;
        t[2] = (_Float16)xv[kc][0].z; t[3] = (_Float16)xv[kc][0].w;
        t[4] = (_Float16)xv[kc][1].x; t[5] = (_Float16)xv[kc][1].y;
        t[6] = (_Float16)xv[kc][1].z; t[7] = (_Float16)xv[kc][1].w;
        bfA[kc] = t;
    }
    __syncthreads();

    // ---- pass A: 9 mt-tiles x 4 kc, all operands LDS/regs
    f32x4 accA[9];
    #pragma unroll
    for (int mt = 0; mt < 9; ++mt) accA[mt] = (f32x4)0.f;
    #pragma unroll
    for (int kc = 0; kc < 4; ++kc) {
        const int k0 = kc * 32 + quad * 8;
        #pragma unroll
        for (int mt = 0; mt < 9; ++mt) {
            const f16x8 af = *(const f16x8*)&Tfl[mt * 16 + col][k0];
            accA[mt] = MFMA(af, bfA[kc], accA[mt], 0, 0, 0);
        }
    }
    #pragma unroll
    for (int mt = 0; mt < 9; ++mt)
        #pragma unroll
        for (int r = 0; r < 4; ++r)
            Y1l[mt * 16 + quad * 4 + r][ic] = (_Float16)accA[mt][r];
    __syncthreads();

    // ---- pass B main: wave wv -> v-tile wv (v = wv*16+col, 0..127)
    f32x4 accB[9];
    #pragma unroll
    for (int mt = 0; mt < 9; ++mt) accB[mt] = (f32x4)0.f;
    #pragma unroll
    for (int kc = 0; kc < 4; ++kc) {
        const int k0 = kc * 32 + quad * 8;
        const f16x8 bf = *(const f16x8*)&Y1l[wv * 16 + col][k0];
        #pragma unroll
        for (int mt = 0; mt < 9; ++mt) {
            const f16x8 af = *(const f16x8*)&Tfl[mt * 16 + col][k0];
            accB[mt] = MFMA(af, bf, accB[mt], 0, 0, 0);
        }
    }
    // ---- tile 8 (v = 128..143, valid 128..131): waves 0..3
    // wave 0: mt {0,1,8}; wave 1: {2,3}; wave 2: {4,5}; wave 3: {6,7}
    f32x4 accT[3];
    #pragma unroll
    for (int j = 0; j < 3; ++j) accT[j] = (f32x4)0.f;
    if (wv < 4) {
        #pragma unroll
        for (int kc = 0; kc < 4; ++kc) {
            const int k0 = kc * 32 + quad * 8;
            const f16x8 bf = *(const f16x8*)&Y1l[128 + col][k0];
            #pragma unroll
            for (int j = 0; j < 3; ++j) {
                if (j < 2 || wv == 0) {
                    const int mt = (j == 2) ? 8 : (wv * 2 + j);
                    const f16x8 af = *(const f16x8*)&Tfl[mt * 16 + col][k0];
                    accT[j] = MFMA(af, bf, accT[j], 0, 0, 0);
                }
            }
        }
    }
    __syncthreads();                     // all Tfl/Y1l reads done

    // ---- restage X into Tfl (now dead): main tiles (v 0..127)
    #pragma unroll
    for (int mt = 0; mt < 9; ++mt)
        #pragma unroll
        for (int r = 0; r < 4; ++r)
            Tfl[mt * 16 + quad * 4 + r][wv * 16 + col] = (_Float16)accB[mt][r];
    // tile 8 (v 128..131)
    if (wv < 4 && col < 4) {
        #pragma unroll
        for (int j = 0; j < 3; ++j) {
            if (j < 2 || wv == 0) {
                const int mt = (j == 2) ? 8 : (wv * 2 + j);
                #pragma unroll
                for (int r = 0; r < 4; ++r)
                    Tfl[mt * 16 + quad * 4 + r][128 + col] = (_Float16)accT[j][r];
            }
        }
    }
    __syncthreads();
    // linear copy-out: 132 rows x 17 f16x8 chunks (cols 132..135 junk, unread)
    _Float16* Xp = X + (size_t)bc * 17952;
    #pragma unroll
    for (int s = 0; s < 5; ++s) {
        const int ch = tid + 512 * s;      // valid < 2244
        if (ch < 2244) {
            const int u = ch / 17, kk = ch - u * 17;
            *(f16x8*)(Xp + u * 136 + kk * 8) = *(const f16x8*)&Tfl[u][kk * 8];
        }
    }
}

// ---------------------------------------------------------- combine MFMA ----
// grid (66 uidx, 8 b), 256 thr (4 waves), 38KB LDS (>=3 blocks/CU, one round).
// Block stages P/M for u1=uidx ONCE and emits rows u1 AND u2=131-uidx
// (h(u2)=g(u1), g(u2)=h(u1), P(u2,v)=P(u1,131-v), M(u2,v)=-M(u1,131-v)).
// kt-split f32 accumulators: cf coefficients applied post-MFMA in f32.
__global__ __launch_bounds__(256, 2) void combine_mfma(
    const _Float16* __restrict__ X, const _Float16* __restrict__ hgT,
    const _Float16* __restrict__ cfT, float* __restrict__ out)
{
    const int uidx = blockIdx.x;    // 0..65
    const int b = blockIdx.y;       // 0..7
    const int tid = threadIdx.x;
    const int wv = tid >> 6, lane = tid & 63;
    const int col = lane & 15, quad = lane >> 4;
    const int u2 = 131 - uidx;
    const bool doB = (uidx >= 4);   // u2 <= 127

    __shared__ _Float16 Ps[132][72];   // [v][c], stride 72 (bank-safe)
    __shared__ _Float16 Ms[132][72];

    // ---- stage P/M for all v in 0..131 (fwd rows as f16x8: v0 % 8 == 0)
    {
        const int c = tid >> 2, sub = tid & 3;
        const _Float16* rowd = X + (size_t)(b * 64 + c) * 17952 + (size_t)uidx * 136;
        const _Float16* rowm = X + (size_t)(b * 64 + c) * 17952 + (size_t)u2 * 136;
        #pragma unroll
        for (int k = 0; k < 4; ++k) {
            const int v0 = sub * 32 + 8 * k;               // multiple of 8
            const f16x8 d  = *(const f16x8*)(rowd + v0);   // X(u1, v0..v0+7)
            const f16x4 mA = *(const f16x4*)(rowm + (128 - v0)); // 131-v for i<4
            const f16x4 mB = *(const f16x4*)(rowm + (124 - v0)); // 131-v for i>=4
            #pragma unroll
            for (int i = 0; i < 4; ++i) {
                Ps[v0 + i][c] = d[i] + mA[3 - i];
                Ms[v0 + i][c] = d[i] - mA[3 - i];
            }
            #pragma unroll
            for (int i = 4; i < 8; ++i) {
                Ps[v0 + i][c] = d[i] + mB[7 - i];
                Ms[v0 + i][c] = d[i] - mB[7 - i];
            }
        }
        if (sub == 0) {                            // tail v = 128..131
            const f16x4 d = *(const f16x4*)(rowd + 128);
            const f16x4 m = *(const f16x4*)(rowm);
            #pragma unroll
            for (int i = 0; i < 4; ++i) {
                Ps[128 + i][c] = d[i] + m[3 - i];
                Ms[128 + i][c] = d[i] - m[3 - i];
            }
        }
    }

    // ---- hoist h/g fragments for u1 (both output rows use them, swapped)
    const _Float16* hgu = hgT + (size_t)uidx * 6 * 4096;
    const int orow = wv * 16 + col;
    f16x8 hA[3][2], gA[3][2];
    #pragma unroll
    for (int kt = 0; kt < 3; ++kt)
        #pragma unroll
        for (int hf = 0; hf < 2; ++hf) {
            hA[kt][hf] = *(const f16x8*)(hgu + ((size_t)kt * 64 + orow) * 64 + hf * 32 + quad * 8);
            gA[kt][hf] = *(const f16x8*)(hgu + ((size_t)(3 + kt) * 64 + orow) * 64 + hf * 32 + quad * 8);
        }
    __syncthreads();

    float* outA = out + (((size_t)(b * 64 + wv * 16 + quad * 4)) * 128 + uidx) * 128 + col;
    float* outB = out + (((size_t)(b * 64 + wv * 16 + quad * 4)) * 128 + u2) * 128 + col;

    #pragma unroll
    for (int nt = 0; nt < 8; ++nt) {
        const int vA = nt * 16 + col;
        const int vB = 131 - vA;
        const f16x8 cf8 = *(const f16x8*)(cfT + (size_t)(nt * 16 + col) * 8);
        const float c1 = (float)cf8[1], c2 = (float)cf8[2];
        const float d1 = (float)cf8[4], d2 = (float)cf8[5];
        {   // output row u1: sum_kt bv_kt*(h_kt (x) P) + bp_kt*(g_kt (x) M)
            const f16x8 p0 = *(const f16x8*)&Ps[vA][quad * 8];
            const f16x8 p1 = *(const f16x8*)&Ps[vA][32 + quad * 8];
            const f16x8 m0 = *(const f16x8*)&Ms[vA][quad * 8];
            const f16x8 m1 = *(const f16x8*)&Ms[vA][32 + quad * 8];
            f32x4 aP0 = (f32x4)0.f, aP1 = (f32x4)0.f, aP2 = (f32x4)0.f;
            f32x4 aM0 = (f32x4)0.f, aM1 = (f32x4)0.f, aM2 = (f32x4)0.f;
            aP0 = MFMA(hA[0][0], p0, aP0, 0, 0, 0); aP0 = MFMA(hA[0][1], p1, aP0, 0, 0, 0);
            aP1 = MFMA(hA[1][0], p0, aP1, 0, 0, 0); aP1 = MFMA(hA[1][1], p1, aP1, 0, 0, 0);
            aP2 = MFMA(hA[2][0], p0, aP2, 0, 0, 0); aP2 = MFMA(hA[2][1], p1, aP2, 0, 0, 0);
            aM0 = MFMA(gA[0][0], m0, aM0, 0, 0, 0); aM0 = MFMA(gA[0][1], m1, aM0, 0, 0, 0);
            aM1 = MFMA(gA[1][0], m0, aM1, 0, 0, 0); aM1 = MFMA(gA[1][1], m1, aM1, 0, 0, 0);
            aM2 = MFMA(gA[2][0], m0, aM2, 0, 0, 0); aM2 = MFMA(gA[2][1], m1, aM2, 0, 0, 0);
            #pragma unroll
            for (int r = 0; r < 4; ++r)
                outA[(size_t)r * 16384 + nt * 16] =
                    ((aP0[r] + c1 * aP1[r] + c2 * aP2[r]) +
                     (aM0[r] + d1 * aM1[r] + d2 * aM2[r])) * SCALE;
        }
        if (doB) {  // output row u2: g on P(rev), h on M(rev), minus M-part
            const f16x8 p0 = *(const f16x8*)&Ps[vB][quad * 8];
            const f16x8 p1 = *(const f16x8*)&Ps[vB][32 + quad * 8];
            const f16x8 m0 = *(const f16x8*)&Ms[vB][quad * 8];
            const f16x8 m1 = *(const f16x8*)&Ms[vB][32 + quad * 8];
            f32x4 bP0 = (f32x4)0.f, bP1 = (f32x4)0.f, bP2 = (f32x4)0.f;
            f32x4 bM0 = (f32x4)0.f, bM1 = (f32x4)0.f, bM2 = (f32x4)0.f;
            bP0 = MFMA(gA[0][0], p0, bP0, 0, 0, 0); bP0 = MFMA(gA[0][1], p1, bP0, 0, 0, 0);
            bP1 = MFMA(gA[1][0], p0, bP1, 0, 0, 0); bP1 = MFMA(gA[1][1], p1, bP1, 0, 0, 0);
            bP2 = MFMA(gA[2][0], p0, bP2, 0, 0, 0); bP2 = MFMA(gA[2][1], p1, bP2, 0, 0, 0);
            bM0 = MFMA(hA[0][0], m0, bM0, 0, 0, 0); bM0 = MFMA(hA[0][1], m1, bM0, 0, 0, 0);
            bM1 = MFMA(hA[1][0], m0, bM1, 0, 0, 0); bM1 = MFMA(hA[1][1], m1, bM1, 0, 0, 0);
            bM2 = MFMA(hA[2][0], m0, bM2, 0, 0, 0); bM2 = MFMA(hA[2][1], m1, bM2, 0, 0, 0);
            #pragma unroll
            for (int r = 0; r < 4; ++r)
                outB[(size_t)r * 16384 + nt * 16] =
                    ((bP0[r] + c1 * bP1[r] + c2 * bP2[r]) -
                     (bM0[r] + d1 * bM1[r] + d2 * bM2[r])) * SCALE;
        }
    }
}

// ----------------------------------------------------------------- launch ----
extern "C" void kernel_launch(void* const* d_in, const int* in_sizes, int n_in,
                              void* d_out, int out_size, void* d_ws, size_t ws_size,
                              hipStream_t stream)
{
    const float* x = (const float*)d_in[0];   // fp32 [8,64,128,128]
    const float* w = (const float*)d_in[1];   // fp32 [64,64,3,3]
    char* ws = (char*)d_ws;
    // byte layout:
    //   cfT f16 @ 36,864     (2,048 B)       [128][8]
    //   X   f16 @ 65,536     (18,382,848 B)  [512][132][136] (cols 132..135 junk)
    //   hgT f16 @ 18,448,384 (3,244,032 B)   [66][6][64][64]
    // total ~21.7 MB
    _Float16* cfT = (_Float16*)(ws + 36864);
    _Float16* X   = (_Float16*)(ws + 65536);
    _Float16* hgT = (_Float16*)(ws + 18448384);

    // launch 1: dht2 (blocks 0..511, in-LDS DHT table) + hgT/cfT prep (512..578)
    dht2_prep<<<dim3(579), dim3(512), 0, stream>>>(x, w, X, cfT, hgT);

    // launch 2: combine as MFMA GEMM, u-paired, 256-thr blocks (no tail round)
    combine_mfma<<<dim3(66, 8), dim3(256), 0, stream>>>(
        X, hgT, cfT, (float*)d_out);
}

// Round 7
// 110.070 us; speedup vs baseline: 1.0362x; 1.0043x over previous
//
#include <hip/hip_runtime.h>
#include <hip/hip_fp16.h>

// HartleyConv2d: out[b,o,u,v] = (0.5/132^2) * sum_c [ X*(W+Wf) + Xf*(W-Wf) ]
// X = DHT2(pad1(x) zero-padded to 132); DHT table T[r][k] = cas(2pi r (k+1)/132).
// ALL I/O fp32: x [8,64,128,128], w [64,64,3,3], out [8,64,128,128].
// R14: isolated combine-occupancy test (dht2 identical to R13). Per-nt
//      SEQUENTIAL u1-then-u2 halves (24 -> 12 live f32 accs, shared cf8) +
//      __launch_bounds__(256,4) -> VGPR<=128 -> 4 blocks/CU -> 528 blocks in
//      ONE round + 16 waves/CU hiding the X-gather staging latency.

#define SCALE (0.5f / 17424.0f)
#define MFMA  __builtin_amdgcn_mfma_f32_16x16x32_f16

typedef __attribute__((ext_vector_type(8))) _Float16 f16x8;
typedef __attribute__((ext_vector_type(4))) _Float16 f16x4;
typedef __attribute__((ext_vector_type(4))) float    f32x4;

// ------------------------------------------------------- dht2_prep ----------
// bid 0..511   : dht2 for plane bc=bid (512 thr, 8 waves)
// bid 512..577 : hgT[u][kt][o][c] for u=bid-512 (all 4096 oc, 8 its of 512)
// bid 578      : cfT [128][8] f16 {1,bv1,bv2,1,bp1,bp2,0,0}
__global__ __launch_bounds__(512, 4) void dht2_prep(
    const float* __restrict__ x, const float* __restrict__ w,
    _Float16* __restrict__ X, _Float16* __restrict__ cfT,
    _Float16* __restrict__ hgT)
{
    const int tid = threadIdx.x;
    const float step = 6.28318530717958647692f / 132.0f;

    if (blockIdx.x >= 512) {
        const int bid2 = blockIdx.x - 512;     // 0..66
        if (bid2 == 66) {                      // ---- cfT
            if (tid < 128) {
                const int v = tid;
                float s, c;
                _Float16 o[8];
                o[0] = (_Float16)1.0f; o[3] = (_Float16)1.0f;
                o[6] = (_Float16)0.0f; o[7] = (_Float16)0.0f;
                sincosf((float)((v * 1) % 132) * step, &s, &c);       o[1] = (_Float16)(c + s);
                sincosf((float)((v * 2) % 132) * step, &s, &c);       o[2] = (_Float16)(c + s);
                sincosf((float)(((v + 1) * 1) % 132) * step, &s, &c); o[4] = (_Float16)(c - s);
                sincosf((float)(((v + 1) * 2) % 132) * step, &s, &c); o[5] = (_Float16)(c - s);
                *(f16x8*)(cfT + v * 8) = *(f16x8*)o;
            }
            return;
        }
        // ---- hgT for u = bid2 (0..65)
        const int u = bid2;
        float a[3], ap[3];
        a[0] = 1.f; ap[0] = 1.f;
        #pragma unroll
        for (int i = 1; i < 3; ++i) {
            float s, c;
            sincosf((float)((u * i) % 132) * step, &s, &c);
            a[i] = c + s;                                   // cas(2pi*u*i/132)
            sincosf((float)(((u + 1) * i) % 132) * step, &s, &c);
            ap[i] = c - s;                                  // cas(-2pi*(u+1)*i/132)
        }
        for (int it = 0; it < 8; ++it) {
            const int oc = it * 512 + tid;                  // o*64+c, 0..4095
            const float* wp = w + (size_t)oc * 9;
            float w9[9];
            #pragma unroll
            for (int q = 0; q < 9; ++q) w9[q] = wp[q];
            #pragma unroll
            for (int j = 0; j < 3; ++j) {
                const float h = a[0]*w9[j] + a[1]*w9[3+j] + a[2]*w9[6+j];
                const float g = ap[0]*w9[j] + ap[1]*w9[3+j] + ap[2]*w9[6+j];
                hgT[((size_t)u * 6 + j)     * 4096 + oc] = (_Float16)h;
                hgT[((size_t)u * 6 + 3 + j) * 4096 + oc] = (_Float16)g;
            }
        }
        return;
    }

    // ------------------------------------------------------ dht2 path ----
    // pass A: wave wv owns i-tile wv: Y1l[v][i] = sum_j Tfl[v][j] * x[i][j]
    // pass B: wave wv owns v-tile wv (0..127); tile 8 (v 128..131) waves 0-3.
    const int bc = blockIdx.x;
    const int wv = tid >> 6, lane = tid & 63;
    const int col = lane & 15, quad = lane >> 4;
    __shared__ _Float16 Tfl[144][136];   // stride 136 (272 B): conflict-minimal
    __shared__ _Float16 Y1l[144][136];
    __shared__ float castab[132];        // cas(2pi*m/132)

    const float* xp = x + (size_t)bc * 16384;
    const int ic = wv * 16 + col;        // this wave's i-column (0..127)

    // ---- hoist x loads for this wave's i-tile (in flight across barriers)
    float4 xv[4][2];
    #pragma unroll
    for (int kc = 0; kc < 4; ++kc) {
        const int k0 = kc * 32 + quad * 8;
        xv[kc][0] = *(const float4*)(xp + ic * 128 + k0);
        xv[kc][1] = *(const float4*)(xp + ic * 128 + k0 + 4);
    }
    // ---- cas table (one sincos per entry, 132 entries over 512 threads)
    if (tid < 132) {
        float s, c;
        sincosf((float)tid * step, &s, &c);
        castab[tid] = c + s;
    }
    __syncthreads();
    // ---- fill Tfl[row][ci] = cas((row*(ci+1)) mod 132), rows >=132 zero
    #pragma unroll
    for (int s = 0; s < 36; ++s) {
        const int idx = s * 512 + tid;       // 0..18431
        const int row = idx >> 7;            // 0..143
        const int ci  = idx & 127;
        float v = 0.f;
        if (row < 132) v = castab[(row * (ci + 1)) % 132];
        Tfl[row][ci] = (_Float16)v;
    }
    // ---- convert x to f16 B-fragments
    f16x8 bfA[4];
    #pragma unroll
    for (int kc = 0; kc < 4; ++kc) {
        f16x8 t;
        t[0] = (_Float16)xv[kc][0].x; t[1] = (_Float16)xv[kc][0].y;
        t[2] = (_Float16)xv[kc][0].z; t[3] = (_Float16)xv[kc][0].w;
        t[4] = (_Float16)xv[kc][1].x; t[5] = (_Float16)xv[kc][1].y;
        t[6] = (_Float16)xv[kc][1].z; t[7] = (_Float16)xv[kc][1].w;
        bfA[kc] = t;
    }
    __syncthreads();

    // ---- pass A: 9 mt-tiles x 4 kc, all operands LDS/regs
    f32x4 accA[9];
    #pragma unroll
    for (int mt = 0; mt < 9; ++mt) accA[mt] = (f32x4)0.f;
    #pragma unroll
    for (int kc = 0; kc < 4; ++kc) {
        const int k0 = kc * 32 + quad * 8;
        #pragma unroll
        for (int mt = 0; mt < 9; ++mt) {
            const f16x8 af = *(const f16x8*)&Tfl[mt * 16 + col][k0];
            accA[mt] = MFMA(af, bfA[kc], accA[mt], 0, 0, 0);
        }
    }
    #pragma unroll
    for (int mt = 0; mt < 9; ++mt)
        #pragma unroll
        for (int r = 0; r < 4; ++r)
            Y1l[mt * 16 + quad * 4 + r][ic] = (_Float16)accA[mt][r];
    __syncthreads();

    // ---- pass B main: wave wv -> v-tile wv (v = wv*16+col, 0..127)
    f32x4 accB[9];
    #pragma unroll
    for (int mt = 0; mt < 9; ++mt) accB[mt] = (f32x4)0.f;
    #pragma unroll
    for (int kc = 0; kc < 4; ++kc) {
        const int k0 = kc * 32 + quad * 8;
        const f16x8 bf = *(const f16x8*)&Y1l[wv * 16 + col][k0];
        #pragma unroll
        for (int mt = 0; mt < 9; ++mt) {
            const f16x8 af = *(const f16x8*)&Tfl[mt * 16 + col][k0];
            accB[mt] = MFMA(af, bf, accB[mt], 0, 0, 0);
        }
    }
    // ---- tile 8 (v = 128..143, valid 128..131): waves 0..3
    // wave 0: mt {0,1,8}; wave 1: {2,3}; wave 2: {4,5}; wave 3: {6,7}
    f32x4 accT[3];
    #pragma unroll
    for (int j = 0; j < 3; ++j) accT[j] = (f32x4)0.f;
    if (wv < 4) {
        #pragma unroll
        for (int kc = 0; kc < 4; ++kc) {
            const int k0 = kc * 32 + quad * 8;
            const f16x8 bf = *(const f16x8*)&Y1l[128 + col][k0];
            #pragma unroll
            for (int j = 0; j < 3; ++j) {
                if (j < 2 || wv == 0) {
                    const int mt = (j == 2) ? 8 : (wv * 2 + j);
                    const f16x8 af = *(const f16x8*)&Tfl[mt * 16 + col][k0];
                    accT[j] = MFMA(af, bf, accT[j], 0, 0, 0);
                }
            }
        }
    }
    __syncthreads();                     // all Tfl/Y1l reads done

    // ---- restage X into Tfl (now dead): main tiles (v 0..127)
    #pragma unroll
    for (int mt = 0; mt < 9; ++mt)
        #pragma unroll
        for (int r = 0; r < 4; ++r)
            Tfl[mt * 16 + quad * 4 + r][wv * 16 + col] = (_Float16)accB[mt][r];
    // tile 8 (v 128..131)
    if (wv < 4 && col < 4) {
        #pragma unroll
        for (int j = 0; j < 3; ++j) {
            if (j < 2 || wv == 0) {
                const int mt = (j == 2) ? 8 : (wv * 2 + j);
                #pragma unroll
                for (int r = 0; r < 4; ++r)
                    Tfl[mt * 16 + quad * 4 + r][128 + col] = (_Float16)accT[j][r];
            }
        }
    }
    __syncthreads();
    // linear copy-out: 132 rows x 17 f16x8 chunks (cols 132..135 junk, unread)
    _Float16* Xp = X + (size_t)bc * 17952;
    #pragma unroll
    for (int s = 0; s < 5; ++s) {
        const int ch = tid + 512 * s;      // valid < 2244
        if (ch < 2244) {
            const int u = ch / 17, kk = ch - u * 17;
            *(f16x8*)(Xp + u * 136 + kk * 8) = *(const f16x8*)&Tfl[u][kk * 8];
        }
    }
}

// ---------------------------------------------------------- combine MFMA ----
// grid (66 uidx, 8 b), 256 thr (4 waves), 38KB LDS, VGPR<=128 via (256,4)
// -> 4 blocks/CU -> all 528 blocks in ONE round, 16 waves/CU latency hiding.
// Block stages P/M for u1=uidx ONCE and emits rows u1 AND u2=131-uidx
// (h(u2)=g(u1), g(u2)=h(u1), P(u2,v)=P(u1,131-v), M(u2,v)=-M(u1,131-v)).
// Per-nt SEQUENTIAL halves: u1's 6 accs -> store -> u2's 6 accs (12 live max,
// cf8 shared by both halves). kt-split f32 accumulators as before.
__global__ __launch_bounds__(256, 4) void combine_mfma(
    const _Float16* __restrict__ X, const _Float16* __restrict__ hgT,
    const _Float16* __restrict__ cfT, float* __restrict__ out)
{
    const int uidx = blockIdx.x;    // 0..65
    const int b = blockIdx.y;       // 0..7
    const int tid = threadIdx.x;
    const int wv = tid >> 6, lane = tid & 63;
    const int col = lane & 15, quad = lane >> 4;
    const int u2 = 131 - uidx;
    const bool doB = (uidx >= 4);   // u2 <= 127

    __shared__ _Float16 Ps[132][72];   // [v][c], stride 72 (bank-safe)
    __shared__ _Float16 Ms[132][72];

    // ---- stage P/M for all v in 0..131 (fwd rows as f16x8: v0 % 8 == 0)
    {
        const int c = tid >> 2, sub = tid & 3;
        const _Float16* rowd = X + (size_t)(b * 64 + c) * 17952 + (size_t)uidx * 136;
        const _Float16* rowm = X + (size_t)(b * 64 + c) * 17952 + (size_t)u2 * 136;
        #pragma unroll
        for (int k = 0; k < 4; ++k) {
            const int v0 = sub * 32 + 8 * k;               // multiple of 8
            const f16x8 d  = *(const f16x8*)(rowd + v0);   // X(u1, v0..v0+7)
            const f16x4 mA = *(const f16x4*)(rowm + (128 - v0)); // 131-v for i<4
            const f16x4 mB = *(const f16x4*)(rowm + (124 - v0)); // 131-v for i>=4
            #pragma unroll
            for (int i = 0; i < 4; ++i) {
                Ps[v0 + i][c] = d[i] + mA[3 - i];
                Ms[v0 + i][c] = d[i] - mA[3 - i];
            }
            #pragma unroll
            for (int i = 4; i < 8; ++i) {
                Ps[v0 + i][c] = d[i] + mB[7 - i];
                Ms[v0 + i][c] = d[i] - mB[7 - i];
            }
        }
        if (sub == 0) {                            // tail v = 128..131
            const f16x4 d = *(const f16x4*)(rowd + 128);
            const f16x4 m = *(const f16x4*)(rowm);
            #pragma unroll
            for (int i = 0; i < 4; ++i) {
                Ps[128 + i][c] = d[i] + m[3 - i];
                Ms[128 + i][c] = d[i] - m[3 - i];
            }
        }
    }

    // ---- hoist h/g fragments for u1 (both output rows use them, swapped)
    const _Float16* hgu = hgT + (size_t)uidx * 6 * 4096;
    const int orow = wv * 16 + col;
    f16x8 hA[3][2], gA[3][2];
    #pragma unroll
    for (int kt = 0; kt < 3; ++kt)
        #pragma unroll
        for (int hf = 0; hf < 2; ++hf) {
            hA[kt][hf] = *(const f16x8*)(hgu + ((size_t)kt * 64 + orow) * 64 + hf * 32 + quad * 8);
            gA[kt][hf] = *(const f16x8*)(hgu + ((size_t)(3 + kt) * 64 + orow) * 64 + hf * 32 + quad * 8);
        }
    __syncthreads();

    float* outA = out + (((size_t)(b * 64 + wv * 16 + quad * 4)) * 128 + uidx) * 128 + col;
    float* outB = out + (((size_t)(b * 64 + wv * 16 + quad * 4)) * 128 + u2) * 128 + col;

    #pragma unroll
    for (int nt = 0; nt < 8; ++nt) {
        const f16x8 cf8 = *(const f16x8*)(cfT + (size_t)(nt * 16 + col) * 8);
        const float c1 = (float)cf8[1], c2 = (float)cf8[2];
        const float d1 = (float)cf8[4], d2 = (float)cf8[5];
        {   // ---- u1 half: sum_kt bv_kt*(h_kt (x) P) + bp_kt*(g_kt (x) M)
            const int vA = nt * 16 + col;
            const f16x8 p0 = *(const f16x8*)&Ps[vA][quad * 8];
            const f16x8 p1 = *(const f16x8*)&Ps[vA][32 + quad * 8];
            const f16x8 m0 = *(const f16x8*)&Ms[vA][quad * 8];
            const f16x8 m1 = *(const f16x8*)&Ms[vA][32 + quad * 8];
            f32x4 aP0 = (f32x4)0.f, aP1 = (f32x4)0.f, aP2 = (f32x4)0.f;
            f32x4 aM0 = (f32x4)0.f, aM1 = (f32x4)0.f, aM2 = (f32x4)0.f;
            aP0 = MFMA(hA[0][0], p0, aP0, 0, 0, 0); aP0 = MFMA(hA[0][1], p1, aP0, 0, 0, 0);
            aP1 = MFMA(hA[1][0], p0, aP1, 0, 0, 0); aP1 = MFMA(hA[1][1], p1, aP1, 0, 0, 0);
            aP2 = MFMA(hA[2][0], p0, aP2, 0, 0, 0); aP2 = MFMA(hA[2][1], p1, aP2, 0, 0, 0);
            aM0 = MFMA(gA[0][0], m0, aM0, 0, 0, 0); aM0 = MFMA(gA[0][1], m1, aM0, 0, 0, 0);
            aM1 = MFMA(gA[1][0], m0, aM1, 0, 0, 0); aM1 = MFMA(gA[1][1], m1, aM1, 0, 0, 0);
            aM2 = MFMA(gA[2][0], m0, aM2, 0, 0, 0); aM2 = MFMA(gA[2][1], m1, aM2, 0, 0, 0);
            #pragma unroll
            for (int r = 0; r < 4; ++r)
                outA[(size_t)r * 16384 + nt * 16] =
                    ((aP0[r] + c1 * aP1[r] + c2 * aP2[r]) +
                     (aM0[r] + d1 * aM1[r] + d2 * aM2[r])) * SCALE;
        }
        if (doB) {  // ---- u2 half: g on P(rev), h on M(rev), minus M-part
            const int vB = 131 - (nt * 16 + col);
            const f16x8 p0 = *(const f16x8*)&Ps[vB][quad * 8];
            const f16x8 p1 = *(const f16x8*)&Ps[vB][32 + quad * 8];
            const f16x8 m0 = *(const f16x8*)&Ms[vB][quad * 8];
            const f16x8 m1 = *(const f16x8*)&Ms[vB][32 + quad * 8];
            f32x4 bP0 = (f32x4)0.f, bP1 = (f32x4)0.f, bP2 = (f32x4)0.f;
            f32x4 bM0 = (f32x4)0.f, bM1 = (f32x4)0.f, bM2 = (f32x4)0.f;
            bP0 = MFMA(gA[0][0], p0, bP0, 0, 0, 0); bP0 = MFMA(gA[0][1], p1, bP0, 0, 0, 0);
            bP1 = MFMA(gA[1][0], p0, bP1, 0, 0, 0); bP1 = MFMA(gA[1][1], p1, bP1, 0, 0, 0);
            bP2 = MFMA(gA[2][0], p0, bP2, 0, 0, 0); bP2 = MFMA(gA[2][1], p1, bP2, 0, 0, 0);
            bM0 = MFMA(hA[0][0], m0, bM0, 0, 0, 0); bM0 = MFMA(hA[0][1], m1, bM0, 0, 0, 0);
            bM1 = MFMA(hA[1][0], m0, bM1, 0, 0, 0); bM1 = MFMA(hA[1][1], m1, bM1, 0, 0, 0);
            bM2 = MFMA(hA[2][0], m0, bM2, 0, 0, 0); bM2 = MFMA(hA[2][1], m1, bM2, 0, 0, 0);
            #pragma unroll
            for (int r = 0; r < 4; ++r)
                outB[(size_t)r * 16384 + nt * 16] =
                    ((bP0[r] + c1 * bP1[r] + c2 * bP2[r]) -
                     (bM0[r] + d1 * bM1[r] + d2 * bM2[r])) * SCALE;
        }
    }
}

// ----------------------------------------------------------------- launch ----
extern "C" void kernel_launch(void* const* d_in, const int* in_sizes, int n_in,
                              void* d_out, int out_size, void* d_ws, size_t ws_size,
                              hipStream_t stream)
{
    const float* x = (const float*)d_in[0];   // fp32 [8,64,128,128]
    const float* w = (const float*)d_in[1];   // fp32 [64,64,3,3]
    char* ws = (char*)d_ws;
    // byte layout:
    //   cfT f16 @ 36,864     (2,048 B)       [128][8]
    //   X   f16 @ 65,536     (18,382,848 B)  [512][132][136] (cols 132..135 junk)
    //   hgT f16 @ 18,448,384 (3,244,032 B)   [66][6][64][64]
    // total ~21.7 MB
    _Float16* cfT = (_Float16*)(ws + 36864);
    _Float16* X   = (_Float16*)(ws + 65536);
    _Float16* hgT = (_Float16*)(ws + 18448384);

    // launch 1: dht2 (blocks 0..511, in-LDS DHT table) + hgT/cfT prep (512..578)
    dht2_prep<<<dim3(579), dim3(512), 0, stream>>>(x, w, X, cfT, hgT);

    // launch 2: combine, u-paired, per-nt sequential halves, 4 blocks/CU
    combine_mfma<<<dim3(66, 8), dim3(256), 0, stream>>>(
        X, hgT, cfT, (float*)d_out);
}

// Round 8
// 109.782 us; speedup vs baseline: 1.0390x; 1.0026x over previous
//
#include <hip/hip_runtime.h>
#include <hip/hip_fp16.h>

// HartleyConv2d: out[b,o,u,v] = (0.5/132^2) * sum_c [ X*(W+Wf) + Xf*(W-Wf) ]
// X = DHT2(pad1(x) zero-padded to 132); DHT table T[r][k] = cas(2pi r (k+1)/132).
// ALL I/O fp32: x [8,64,128,128], w [64,64,3,3], out [8,64,128,128].
// R15: P/M fold moved INTO dht2's epilogue (plane-local: P(u,v)=X(u,v)+
//      X(131-u,131-v) uses two rows of the SAME plane, already in LDS).
//      dht2 writes P[66][136]+M[66][136] per plane (same bytes as X[132][136]);
//      combine staging becomes pure linear b128 copy (no reversed loads, no
//      fold VALU, ~8MB less read traffic). Rest identical to R14 (110.07us).

#define SCALE (0.5f / 17424.0f)
#define MFMA  __builtin_amdgcn_mfma_f32_16x16x32_f16

typedef __attribute__((ext_vector_type(8))) _Float16 f16x8;
typedef __attribute__((ext_vector_type(4))) _Float16 f16x4;
typedef __attribute__((ext_vector_type(4))) float    f32x4;

// ------------------------------------------------------- dht2_prep ----------
// bid 0..511   : dht2 for plane bc=bid (512 thr, 8 waves) -> P/M planes
// bid 512..577 : hgT[u][kt][o][c] for u=bid-512 (all 4096 oc, 8 its of 512)
// bid 578      : cfT [128][8] f16 {1,bv1,bv2,1,bp1,bp2,0,0}
__global__ __launch_bounds__(512, 4) void dht2_prep(
    const float* __restrict__ x, const float* __restrict__ w,
    _Float16* __restrict__ PM, _Float16* __restrict__ cfT,
    _Float16* __restrict__ hgT)
{
    const int tid = threadIdx.x;
    const float step = 6.28318530717958647692f / 132.0f;

    if (blockIdx.x >= 512) {
        const int bid2 = blockIdx.x - 512;     // 0..66
        if (bid2 == 66) {                      // ---- cfT
            if (tid < 128) {
                const int v = tid;
                float s, c;
                _Float16 o[8];
                o[0] = (_Float16)1.0f; o[3] = (_Float16)1.0f;
                o[6] = (_Float16)0.0f; o[7] = (_Float16)0.0f;
                sincosf((float)((v * 1) % 132) * step, &s, &c);       o[1] = (_Float16)(c + s);
                sincosf((float)((v * 2) % 132) * step, &s, &c);       o[2] = (_Float16)(c + s);
                sincosf((float)(((v + 1) * 1) % 132) * step, &s, &c); o[4] = (_Float16)(c - s);
                sincosf((float)(((v + 1) * 2) % 132) * step, &s, &c); o[5] = (_Float16)(c - s);
                *(f16x8*)(cfT + v * 8) = *(f16x8*)o;
            }
            return;
        }
        // ---- hgT for u = bid2 (0..65)
        const int u = bid2;
        float a[3], ap[3];
        a[0] = 1.f; ap[0] = 1.f;
        #pragma unroll
        for (int i = 1; i < 3; ++i) {
            float s, c;
            sincosf((float)((u * i) % 132) * step, &s, &c);
            a[i] = c + s;                                   // cas(2pi*u*i/132)
            sincosf((float)(((u + 1) * i) % 132) * step, &s, &c);
            ap[i] = c - s;                                  // cas(-2pi*(u+1)*i/132)
        }
        for (int it = 0; it < 8; ++it) {
            const int oc = it * 512 + tid;                  // o*64+c, 0..4095
            const float* wp = w + (size_t)oc * 9;
            float w9[9];
            #pragma unroll
            for (int q = 0; q < 9; ++q) w9[q] = wp[q];
            #pragma unroll
            for (int j = 0; j < 3; ++j) {
                const float h = a[0]*w9[j] + a[1]*w9[3+j] + a[2]*w9[6+j];
                const float g = ap[0]*w9[j] + ap[1]*w9[3+j] + ap[2]*w9[6+j];
                hgT[((size_t)u * 6 + j)     * 4096 + oc] = (_Float16)h;
                hgT[((size_t)u * 6 + 3 + j) * 4096 + oc] = (_Float16)g;
            }
        }
        return;
    }

    // ------------------------------------------------------ dht2 path ----
    // pass A: wave wv owns i-tile wv: Y1l[v][i] = sum_j Tfl[v][j] * x[i][j]
    // pass B: wave wv owns v-tile wv (0..127); tile 8 (v 128..131) waves 0-3.
    const int bc = blockIdx.x;
    const int wv = tid >> 6, lane = tid & 63;
    const int col = lane & 15, quad = lane >> 4;
    __shared__ _Float16 Tfl[144][136];   // stride 136 (272 B): conflict-minimal
    __shared__ _Float16 Y1l[144][136];
    __shared__ float castab[132];        // cas(2pi*m/132)

    const float* xp = x + (size_t)bc * 16384;
    const int ic = wv * 16 + col;        // this wave's i-column (0..127)

    // ---- hoist x loads for this wave's i-tile (in flight across barriers)
    float4 xv[4][2];
    #pragma unroll
    for (int kc = 0; kc < 4; ++kc) {
        const int k0 = kc * 32 + quad * 8;
        xv[kc][0] = *(const float4*)(xp + ic * 128 + k0);
        xv[kc][1] = *(const float4*)(xp + ic * 128 + k0 + 4);
    }
    // ---- cas table (one sincos per entry, 132 entries over 512 threads)
    if (tid < 132) {
        float s, c;
        sincosf((float)tid * step, &s, &c);
        castab[tid] = c + s;
    }
    __syncthreads();
    // ---- fill Tfl[row][ci] = cas((row*(ci+1)) mod 132), rows >=132 zero
    #pragma unroll
    for (int s = 0; s < 36; ++s) {
        const int idx = s * 512 + tid;       // 0..18431
        const int row = idx >> 7;            // 0..143
        const int ci  = idx & 127;
        float v = 0.f;
        if (row < 132) v = castab[(row * (ci + 1)) % 132];
        Tfl[row][ci] = (_Float16)v;
    }
    // ---- convert x to f16 B-fragments
    f16x8 bfA[4];
    #pragma unroll
    for (int kc = 0; kc < 4; ++kc) {
        f16x8 t;
        t[0] = (_Float16)xv[kc][0].x; t[1] = (_Float16)xv[kc][0].y;
        t[2] = (_Float16)xv[kc][0].z; t[3] = (_Float16)xv[kc][0].w;
        t[4] = (_Float16)xv[kc][1].x; t[5] = (_Float16)xv[kc][1].y;
        t[6] = (_Float16)xv[kc][1].z; t[7] = (_Float16)xv[kc][1].w;
        bfA[kc] = t;
    }
    __syncthreads();

    // ---- pass A: 9 mt-tiles x 4 kc, all operands LDS/regs
    f32x4 accA[9];
    #pragma unroll
    for (int mt = 0; mt < 9; ++mt) accA[mt] = (f32x4)0.f;
    #pragma unroll
    for (int kc = 0; kc < 4; ++kc) {
        const int k0 = kc * 32 + quad * 8;
        #pragma unroll
        for (int mt = 0; mt < 9; ++mt) {
            const f16x8 af = *(const f16x8*)&Tfl[mt * 16 + col][k0];
            accA[mt] = MFMA(af, bfA[kc], accA[mt], 0, 0, 0);
        }
    }
    #pragma unroll
    for (int mt = 0; mt < 9; ++mt)
        #pragma unroll
        for (int r = 0; r < 4; ++r)
            Y1l[mt * 16 + quad * 4 + r][ic] = (_Float16)accA[mt][r];
    __syncthreads();

    // ---- pass B main: wave wv -> v-tile wv (v = wv*16+col, 0..127)
    f32x4 accB[9];
    #pragma unroll
    for (int mt = 0; mt < 9; ++mt) accB[mt] = (f32x4)0.f;
    #pragma unroll
    for (int kc = 0; kc < 4; ++kc) {
        const int k0 = kc * 32 + quad * 8;
        const f16x8 bf = *(const f16x8*)&Y1l[wv * 16 + col][k0];
        #pragma unroll
        for (int mt = 0; mt < 9; ++mt) {
            const f16x8 af = *(const f16x8*)&Tfl[mt * 16 + col][k0];
            accB[mt] = MFMA(af, bf, accB[mt], 0, 0, 0);
        }
    }
    // ---- tile 8 (v = 128..143, valid 128..131): waves 0..3
    // wave 0: mt {0,1,8}; wave 1: {2,3}; wave 2: {4,5}; wave 3: {6,7}
    f32x4 accT[3];
    #pragma unroll
    for (int j = 0; j < 3; ++j) accT[j] = (f32x4)0.f;
    if (wv < 4) {
        #pragma unroll
        for (int kc = 0; kc < 4; ++kc) {
            const int k0 = kc * 32 + quad * 8;
            const f16x8 bf = *(const f16x8*)&Y1l[128 + col][k0];
            #pragma unroll
            for (int j = 0; j < 3; ++j) {
                if (j < 2 || wv == 0) {
                    const int mt = (j == 2) ? 8 : (wv * 2 + j);
                    const f16x8 af = *(const f16x8*)&Tfl[mt * 16 + col][k0];
                    accT[j] = MFMA(af, bf, accT[j], 0, 0, 0);
                }
            }
        }
    }
    __syncthreads();                     // all Tfl/Y1l reads done

    // ---- restage X into Tfl (now dead): main tiles (v 0..127)
    #pragma unroll
    for (int mt = 0; mt < 9; ++mt)
        #pragma unroll
        for (int r = 0; r < 4; ++r)
            Tfl[mt * 16 + quad * 4 + r][wv * 16 + col] = (_Float16)accB[mt][r];
    // tile 8 (v 128..131)
    if (wv < 4 && col < 4) {
        #pragma unroll
        for (int j = 0; j < 3; ++j) {
            if (j < 2 || wv == 0) {
                const int mt = (j == 2) ? 8 : (wv * 2 + j);
                #pragma unroll
                for (int r = 0; r < 4; ++r)
                    Tfl[mt * 16 + quad * 4 + r][128 + col] = (_Float16)accT[j][r];
            }
        }
    }
    __syncthreads();

    // ---- P/M fold + linear copy-out: 66 rows x 17 chunks = 1122 over 512 thr
    // P[u][v] = X[u][v] + X[131-u][131-v]; M = difference. Cols 132..135 junk.
    _Float16* Pp = PM + (size_t)bc * 17952;          // P: 66*136, M follows
    _Float16* Mp = Pp + 8976;
    #pragma unroll
    for (int s = 0; s < 3; ++s) {
        const int ch = tid + 512 * s;
        if (ch < 1122) {
            const int u = ch / 17, kk = ch - u * 17;
            const int ur = 131 - u;
            const f16x8 f = *(const f16x8*)&Tfl[u][kk * 8];
            f16x8 p, m;
            if (kk < 16) {
                const int base = 124 - kk * 8;
                const f16x4 rA = *(const f16x4*)&Tfl[ur][base + 4]; // rev i<4
                const f16x4 rB = *(const f16x4*)&Tfl[ur][base];     // rev i>=4
                #pragma unroll
                for (int i = 0; i < 4; ++i) {
                    p[i] = f[i] + rA[3 - i];  m[i] = f[i] - rA[3 - i];
                }
                #pragma unroll
                for (int i = 4; i < 8; ++i) {
                    p[i] = f[i] + rB[7 - i];  m[i] = f[i] - rB[7 - i];
                }
            } else {                            // v = 128..131 valid, rest junk
                const f16x4 rA = *(const f16x4*)&Tfl[ur][0];
                #pragma unroll
                for (int i = 0; i < 4; ++i) {
                    p[i] = f[i] + rA[3 - i];  m[i] = f[i] - rA[3 - i];
                }
                #pragma unroll
                for (int i = 4; i < 8; ++i) { p[i] = (_Float16)0.f; m[i] = (_Float16)0.f; }
            }
            *(f16x8*)(Pp + u * 136 + kk * 8) = p;
            *(f16x8*)(Mp + u * 136 + kk * 8) = m;
        }
    }
}

// ---------------------------------------------------------- combine MFMA ----
// grid (66 uidx, 8 b), 256 thr (4 waves), 38KB LDS, (256,4) -> 4 blocks/CU.
// P/M pre-folded by dht2: staging is a pure LINEAR b128 copy (no reversed
// loads, no fold VALU). Block emits rows u1=uidx AND u2=131-uidx from the
// same Ps/Ms (h(u2)=g(u1), g(u2)=h(u1), P(u2,v)=P(u1,131-v), M(u2,v)=
// -M(u1,131-v)). Per-nt sequential u1/u2 halves, kt-split f32 accumulators.
__global__ __launch_bounds__(256, 4) void combine_mfma(
    const _Float16* __restrict__ PM, const _Float16* __restrict__ hgT,
    const _Float16* __restrict__ cfT, float* __restrict__ out)
{
    const int uidx = blockIdx.x;    // 0..65
    const int b = blockIdx.y;       // 0..7
    const int tid = threadIdx.x;
    const int wv = tid >> 6, lane = tid & 63;
    const int col = lane & 15, quad = lane >> 4;
    const int u2 = 131 - uidx;
    const bool doB = (uidx >= 4);   // u2 <= 127

    __shared__ _Float16 Ps[132][72];   // [v][c], stride 72 (bank-safe)
    __shared__ _Float16 Ms[132][72];

    // ---- stage P/M: pure linear copy (8 b128 loads + tail per thread)
    {
        const int c = tid >> 2, sub = tid & 3;
        const _Float16* Pp = PM + (size_t)(b * 64 + c) * 17952 + (size_t)uidx * 136;
        const _Float16* Mp = Pp + 8976;
        #pragma unroll
        for (int k = 0; k < 4; ++k) {
            const int v0 = sub * 32 + 8 * k;
            const f16x8 p = *(const f16x8*)(Pp + v0);
            const f16x8 m = *(const f16x8*)(Mp + v0);
            #pragma unroll
            for (int i = 0; i < 8; ++i) {
                Ps[v0 + i][c] = p[i];
                Ms[v0 + i][c] = m[i];
            }
        }
        if (sub == 0) {                            // tail v = 128..131
            const f16x4 p = *(const f16x4*)(Pp + 128);
            const f16x4 m = *(const f16x4*)(Mp + 128);
            #pragma unroll
            for (int i = 0; i < 4; ++i) {
                Ps[128 + i][c] = p[i];
                Ms[128 + i][c] = m[i];
            }
        }
    }

    // ---- hoist h/g fragments for u1 (both output rows use them, swapped)
    const _Float16* hgu = hgT + (size_t)uidx * 6 * 4096;
    const int orow = wv * 16 + col;
    f16x8 hA[3][2], gA[3][2];
    #pragma unroll
    for (int kt = 0; kt < 3; ++kt)
        #pragma unroll
        for (int hf = 0; hf < 2; ++hf) {
            hA[kt][hf] = *(const f16x8*)(hgu + ((size_t)kt * 64 + orow) * 64 + hf * 32 + quad * 8);
            gA[kt][hf] = *(const f16x8*)(hgu + ((size_t)(3 + kt) * 64 + orow) * 64 + hf * 32 + quad * 8);
        }
    __syncthreads();

    float* outA = out + (((size_t)(b * 64 + wv * 16 + quad * 4)) * 128 + uidx) * 128 + col;
    float* outB = out + (((size_t)(b * 64 + wv * 16 + quad * 4)) * 128 + u2) * 128 + col;

    #pragma unroll
    for (int nt = 0; nt < 8; ++nt) {
        const f16x8 cf8 = *(const f16x8*)(cfT + (size_t)(nt * 16 + col) * 8);
        const float c1 = (float)cf8[1], c2 = (float)cf8[2];
        const float d1 = (float)cf8[4], d2 = (float)cf8[5];
        {   // ---- u1 half: sum_kt bv_kt*(h_kt (x) P) + bp_kt*(g_kt (x) M)
            const int vA = nt * 16 + col;
            const f16x8 p0 = *(const f16x8*)&Ps[vA][quad * 8];
            const f16x8 p1 = *(const f16x8*)&Ps[vA][32 + quad * 8];
            const f16x8 m0 = *(const f16x8*)&Ms[vA][quad * 8];
            const f16x8 m1 = *(const f16x8*)&Ms[vA][32 + quad * 8];
            f32x4 aP0 = (f32x4)0.f, aP1 = (f32x4)0.f, aP2 = (f32x4)0.f;
            f32x4 aM0 = (f32x4)0.f, aM1 = (f32x4)0.f, aM2 = (f32x4)0.f;
            aP0 = MFMA(hA[0][0], p0, aP0, 0, 0, 0); aP0 = MFMA(hA[0][1], p1, aP0, 0, 0, 0);
            aP1 = MFMA(hA[1][0], p0, aP1, 0, 0, 0); aP1 = MFMA(hA[1][1], p1, aP1, 0, 0, 0);
            aP2 = MFMA(hA[2][0], p0, aP2, 0, 0, 0); aP2 = MFMA(hA[2][1], p1, aP2, 0, 0, 0);
            aM0 = MFMA(gA[0][0], m0, aM0, 0, 0, 0); aM0 = MFMA(gA[0][1], m1, aM0, 0, 0, 0);
            aM1 = MFMA(gA[1][0], m0, aM1, 0, 0, 0); aM1 = MFMA(gA[1][1], m1, aM1, 0, 0, 0);
            aM2 = MFMA(gA[2][0], m0, aM2, 0, 0, 0); aM2 = MFMA(gA[2][1], m1, aM2, 0, 0, 0);
            #pragma unroll
            for (int r = 0; r < 4; ++r)
                outA[(size_t)r * 16384 + nt * 16] =
                    ((aP0[r] + c1 * aP1[r] + c2 * aP2[r]) +
                     (aM0[r] + d1 * aM1[r] + d2 * aM2[r])) * SCALE;
        }
        if (doB) {  // ---- u2 half: g on P(rev), h on M(rev), minus M-part
            const int vB = 131 - (nt * 16 + col);
            const f16x8 p0 = *(const f16x8*)&Ps[vB][quad * 8];
            const f16x8 p1 = *(const f16x8*)&Ps[vB][32 + quad * 8];
            const f16x8 m0 = *(const f16x8*)&Ms[vB][quad * 8];
            const f16x8 m1 = *(const f16x8*)&Ms[vB][32 + quad * 8];
            f32x4 bP0 = (f32x4)0.f, bP1 = (f32x4)0.f, bP2 = (f32x4)0.f;
            f32x4 bM0 = (f32x4)0.f, bM1 = (f32x4)0.f, bM2 = (f32x4)0.f;
            bP0 = MFMA(gA[0][0], p0, bP0, 0, 0, 0); bP0 = MFMA(gA[0][1], p1, bP0, 0, 0, 0);
            bP1 = MFMA(gA[1][0], p0, bP1, 0, 0, 0); bP1 = MFMA(gA[1][1], p1, bP1, 0, 0, 0);
            bP2 = MFMA(gA[2][0], p0, bP2, 0, 0, 0); bP2 = MFMA(gA[2][1], p1, bP2, 0, 0, 0);
            bM0 = MFMA(hA[0][0], m0, bM0, 0, 0, 0); bM0 = MFMA(hA[0][1], m1, bM0, 0, 0, 0);
            bM1 = MFMA(hA[1][0], m0, bM1, 0, 0, 0); bM1 = MFMA(hA[1][1], m1, bM1, 0, 0, 0);
            bM2 = MFMA(hA[2][0], m0, bM2, 0, 0, 0); bM2 = MFMA(hA[2][1], m1, bM2, 0, 0, 0);
            #pragma unroll
            for (int r = 0; r < 4; ++r)
                outB[(size_t)r * 16384 + nt * 16] =
                    ((bP0[r] + c1 * bP1[r] + c2 * bP2[r]) -
                     (bM0[r] + d1 * bM1[r] + d2 * bM2[r])) * SCALE;
        }
    }
}

// ----------------------------------------------------------------- launch ----
extern "C" void kernel_launch(void* const* d_in, const int* in_sizes, int n_in,
                              void* d_out, int out_size, void* d_ws, size_t ws_size,
                              hipStream_t stream)
{
    const float* x = (const float*)d_in[0];   // fp32 [8,64,128,128]
    const float* w = (const float*)d_in[1];   // fp32 [64,64,3,3]
    char* ws = (char*)d_ws;
    // byte layout:
    //   cfT f16 @ 36,864     (2,048 B)       [128][8]
    //   PM  f16 @ 65,536     (18,382,848 B)  [512][2][66][136] (P then M)
    //   hgT f16 @ 18,448,384 (3,244,032 B)   [66][6][64][64]
    // total ~21.7 MB
    _Float16* cfT = (_Float16*)(ws + 36864);
    _Float16* PM  = (_Float16*)(ws + 65536);
    _Float16* hgT = (_Float16*)(ws + 18448384);

    // launch 1: dht2 + P/M fold (blocks 0..511) + hgT/cfT prep (512..578)
    dht2_prep<<<dim3(579), dim3(512), 0, stream>>>(x, w, PM, cfT, hgT);

    // launch 2: combine, u-paired, linear staging, per-nt sequential halves
    combine_mfma<<<dim3(66, 8), dim3(256), 0, stream>>>(
        PM, hgT, cfT, (float*)d_out);
}